// Round 5
// baseline (271.357 us; speedup 1.0000x reference)
//
#include <hip/hip_runtime.h>
#include <cstdint>

#define LRELU_ALPHA 0.2f
#define NEG_INF -9000000000000000.0f
#define L2E 1.4426950408889634f

typedef __bf16 bf16x8 __attribute__((ext_vector_type(8)));
typedef float floatx4 __attribute__((ext_vector_type(4)));
typedef unsigned int uintx4 __attribute__((ext_vector_type(4)));

constexpr int Bb = 8, Nn = 2048, Ff = 64;
constexpr int TJ = 64;             // j-tile width
constexpr int SEGW = 8;            // waves per block = in-block j-slices
constexpr int SLICE = Nn / SEGW;   // 256 j per wave
constexpr int NT = SLICE / TJ;     // 4 tiles per wave
constexpr int NROWS = Bb * Nn;     // 16384 global rows
constexpr int MCH = Nn / 64;       // 32 mask chunks per row

__device__ __forceinline__ unsigned short f2bf(float f) {
    unsigned u = __builtin_bit_cast(unsigned, f);
    u = u + 0x7FFFu + ((u >> 16) & 1u);   // round-to-nearest-even
    return (unsigned short)(u >> 16);
}

__device__ __forceinline__ unsigned cvt_pk_bf16(float lo, float hi) {
    unsigned r;
    asm("v_cvt_pk_bf16_f32 %0, %1, %2" : "=v"(r) : "v"(lo), "v"(hi));
    return r;
}

// ---------------- Kernel 1: h = x@W (fp32), s1 = h.a1, s2 = h.a2, hT (bf16, transposed) ----
__global__ __launch_bounds__(256) void gat_prep(
    const float* __restrict__ x, const float* __restrict__ W, const float* __restrict__ a,
    unsigned short* __restrict__ hT, float* __restrict__ s1g, float* __restrict__ s2g)
{
    constexpr int STR2 = 36;                    // [f][il] stride (bank-stride 18 -> 2-way = free)
    __shared__ unsigned short hblk[64 * STR2];
    const int tid = threadIdx.x;
    const int blk = blockIdx.x;                 // 512 blocks: 64 row-blocks x 8 batches
    const int b  = blk >> 6;
    const int i0 = (blk & 63) * 32;
    const int w    = tid >> 6;
    const int lane = tid & 63;                  // lane = output feature f

    float wcol[64];
    #pragma unroll
    for (int k = 0; k < 64; ++k) wcol[k] = W[k * 64 + lane];
    const float a1 = a[lane], a2 = a[64 + lane];

    for (int r = 0; r < 8; ++r) {
        const int il = w * 8 + r;
        const int i  = i0 + il;
        const float* xrow = x + ((size_t)(b * Nn + i)) * 64;   // wave-uniform -> s_loads
        float h0 = 0.f, h1 = 0.f, h2 = 0.f, h3 = 0.f;
        #pragma unroll
        for (int k = 0; k < 64; k += 4) {
            h0 = fmaf(xrow[k],     wcol[k],     h0);
            h1 = fmaf(xrow[k + 1], wcol[k + 1], h1);
            h2 = fmaf(xrow[k + 2], wcol[k + 2], h2);
            h3 = fmaf(xrow[k + 3], wcol[k + 3], h3);
        }
        const float h = (h0 + h1) + (h2 + h3);
        float p1 = h * a1, p2 = h * a2;
        #pragma unroll
        for (int off = 32; off; off >>= 1) {
            p1 += __shfl_xor(p1, off);
            p2 += __shfl_xor(p2, off);
        }
        if (lane == 0) { s1g[b * Nn + i] = p1; s2g[b * Nn + i] = p2; }
        hblk[lane * STR2 + il] = f2bf(h);          // transpose via LDS
    }
    __syncthreads();
    {
        const int f = tid >> 2, c = (tid & 3) * 8;
        uint4 v = *reinterpret_cast<const uint4*>(&hblk[f * STR2 + c]);
        *reinterpret_cast<uint4*>(hT + ((size_t)b * 64 + f) * Nn + i0 + c) = v;
    }
}

// ---------------- Kernel 0b: adj -> bitmask pack + EXACT row max (monotonic leaky trick) --
// Streams 134 MB coalesced; emits masks[row][chunk] (4 MB) AND
// row_m[row] = leaky(s1[row] + max_{j in N(row)} s2[j])  — the TRUE softmax row max,
// valid because leaky_relu is monotonic. Runs after gat_prep (needs s1,s2; both L2-hot).
__global__ __launch_bounds__(256) void gat_pack(
    const int* __restrict__ adj, const float* __restrict__ s1g, const float* __restrict__ s2g,
    unsigned long long* __restrict__ masks, float* __restrict__ row_m)
{
    const int wid  = blockIdx.x * 4 + (threadIdx.x >> 6);
    const int lane = threadIdx.x & 63;
    #pragma unroll
    for (int rr = 0; rr < 2; ++rr) {
        const int row = wid * 2 + rr;
        const int b   = row >> 11;
        const int* ar = adj + (size_t)row * Nn;
        const float* s2r = s2g + (size_t)b * Nn;
        unsigned long long acc = 0;            // lane c (<32) accumulates chunk c's mask
        float mx = NEG_INF;
        #pragma unroll
        for (int cb = 0; cb < MCH; ++cb) {
            const int   v  = ar[cb * 64 + lane];
            const float sv = s2r[cb * 64 + lane];       // L2-resident (64 KB total)
            const unsigned long long mb = __ballot(v > 0);   // bit l <-> j = cb*64+l
            if (lane == cb) acc = mb;
            mx = (v > 0) ? fmaxf(mx, sv) : mx;
        }
        #pragma unroll
        for (int off = 32; off; off >>= 1) mx = fmaxf(mx, __shfl_xor(mx, off));
        if (lane < 32) masks[(size_t)row * MCH + lane] = acc;   // 256 B coalesced
        if (lane == 0) {
            const float ev = s1g[row] + mx;
            row_m[row] = fmaxf(ev, LRELU_ALPHA * ev);           // leaky(s1 + max s2)
        }
    }
}

// ---------------- Kernel 2: fused attention, NO online softmax (global row max known) -----
// Block = 512 threads = 8 waves; block owns 16 rows; wave s sweeps j-slice [s*256,(s+1)*256).
// Per tile: 8 B mask + 32 B s2 + 8 bf16x8 B-frags, then p = mask ? exp2(ev-m_i) : 0 directly
// (p <= 1 guaranteed), accumulate l and C. Tiles FULLY independent -> deep pipelining.
// One l-reduce per wave (2 shuffles). ONE barrier; sum-only merge; normalize+ELU -> out.
__global__ __launch_bounds__(512, 4) void gat_attn(
    const unsigned long long* __restrict__ masks, const unsigned short* __restrict__ hT,
    const float* __restrict__ s1g, const float* __restrict__ s2g,
    const float* __restrict__ row_m, float* __restrict__ out)
{
    __shared__ float O_lds[SEGW][16][65];
    __shared__ float l_lds[SEGW][16];

    const int tid  = threadIdx.x;
    const int blk  = blockIdx.x;          // 1024 blocks: 128 per batch
    const int b    = blk >> 7;
    const int i0   = (blk & 127) * 16;
    const int s    = tid >> 6;            // wave id = j-slice
    const int lane = tid & 63;
    const int fl   = lane & 15;           // A-row (i) in e-phase; B-col (f) in mfma phase
    const int q    = lane >> 4;           // quad id: k-group selector

    const int i = i0 + fl;                // this lane's score row
    const float s1v = s1g[b * Nn + i];
    const float ci  = -row_m[b * Nn + i] * L2E;          // exp2 arg bias (exact row max)
    const unsigned short* hTb = hT + (size_t)b * 64 * Nn + s * SLICE;
    const float* s2b = s2g + b * Nn + s * SLICE;
    const unsigned long long* mrow = masks + (size_t)(b * Nn + i) * MCH + s * NT;

    float l = 0.f;
    floatx4 C[4] = {};                    // 4 f-tiles of 16x16 C

    #pragma unroll
    for (int jt = 0; jt < NT; ++jt) {
        const int jloc = jt * TJ;

        const unsigned long long mk = mrow[jt];
        const float4 sA = *reinterpret_cast<const float4*>(&s2b[jloc + q * 8]);
        const float4 sB = *reinterpret_cast<const float4*>(&s2b[jloc + q * 8 + 4]);
        const float4 sC = *reinterpret_cast<const float4*>(&s2b[jloc + 32 + q * 8]);
        const float4 sD = *reinterpret_cast<const float4*>(&s2b[jloc + 32 + q * 8 + 4]);

        bf16x8 Bv[8];
        #pragma unroll
        for (int u = 0; u < 4; ++u) {
            Bv[2 * u] = *reinterpret_cast<const bf16x8*>(
                hTb + (size_t)(u * 16 + fl) * Nn + jloc + q * 8);
            Bv[2 * u + 1] = *reinterpret_cast<const bf16x8*>(
                hTb + (size_t)(u * 16 + fl) * Nn + jloc + 32 + q * 8);
        }

        const unsigned blo = ((unsigned)(mk >> (q * 8))) & 0xFFu;
        const unsigned bhi = ((unsigned)(mk >> (32 + q * 8))) & 0xFFu;

        // p[k]: j = jloc + tt*32 + q*8 + jj ; p = mask ? exp(e - m_i) : 0 ; p <= 1
        float p[16];
        {
            const float s2v0[8] = { sA.x, sA.y, sA.z, sA.w, sB.x, sB.y, sB.z, sB.w };
            const float s2v1[8] = { sC.x, sC.y, sC.z, sC.w, sD.x, sD.y, sD.z, sD.w };
            #pragma unroll
            for (int jj = 0; jj < 8; ++jj) {
                float ev = s1v + s2v0[jj];
                ev = fmaxf(ev, LRELU_ALPHA * ev);              // leaky_relu, alpha<1
                const float t = exp2f(fmaf(ev, L2E, ci));
                p[jj] = (blo & (1u << jj)) ? t : 0.f;
                l += p[jj];
            }
            #pragma unroll
            for (int jj = 0; jj < 8; ++jj) {
                float ev = s1v + s2v1[jj];
                ev = fmaxf(ev, LRELU_ALPHA * ev);
                const float t = exp2f(fmaf(ev, L2E, ci));
                p[8 + jj] = (bhi & (1u << jj)) ? t : 0.f;
                l += p[8 + jj];
            }
        }

        // pack p -> bf16 A-fragments
        uintx4 pa, pb;
        #pragma unroll
        for (int d = 0; d < 4; ++d) {
            pa[d] = cvt_pk_bf16(p[2 * d],     p[2 * d + 1]);
            pb[d] = cvt_pk_bf16(p[8 + 2 * d], p[8 + 2 * d + 1]);
        }
        const bf16x8 A0 = __builtin_bit_cast(bf16x8, pa);
        const bf16x8 A1 = __builtin_bit_cast(bf16x8, pb);

        // PV: 4 f-tiles x 2 k-steps
        __builtin_amdgcn_s_setprio(1);
        #pragma unroll
        for (int u = 0; u < 4; ++u) {
            C[u] = __builtin_amdgcn_mfma_f32_16x16x32_bf16(A0, Bv[2 * u],     C[u], 0, 0, 0);
            C[u] = __builtin_amdgcn_mfma_f32_16x16x32_bf16(A1, Bv[2 * u + 1], C[u], 0, 0, 0);
        }
        __builtin_amdgcn_s_setprio(0);
    }

    // one l-reduce per wave (cross-quad), not per tile
    l += __shfl_xor(l, 16);
    l += __shfl_xor(l, 32);

    // ---- in-block merge of the 8 j-slice partials (sum-only: all share m_i) ----
    #pragma unroll
    for (int u = 0; u < 4; ++u)
        #pragma unroll
        for (int r = 0; r < 4; ++r)
            O_lds[s][q * 4 + r][u * 16 + fl] = C[u][r];
    if (q == 0) l_lds[s][fl] = l;
    __syncthreads();

    // 1024 outputs, 512 threads -> 2 consecutive f each; coalesced float2 store
    const int row = tid >> 5;
    const int f0  = (tid & 31) * 2;

    float lsum = 0.f, acc0 = 0.f, acc1 = 0.f;
    #pragma unroll
    for (int k = 0; k < SEGW; ++k) {
        lsum += l_lds[k][row];
        const float2 ov = *reinterpret_cast<const float2*>(&O_lds[k][row][f0]);
        acc0 += ov.x;
        acc1 += ov.y;
    }
    const float inv = 1.f / lsum;
    float v0 = acc0 * inv, v1 = acc1 * inv;
    v0 = (v0 > 0.f) ? v0 : (exp2f(v0 * L2E) - 1.f);    // elu, alpha=1
    v1 = (v1 > 0.f) ? v1 : (exp2f(v1 * L2E) - 1.f);
    float2 o2; o2.x = v0; o2.y = v1;
    *reinterpret_cast<float2*>(&out[((size_t)(b * Nn + i0 + row)) * 64 + f0]) = o2;
}

extern "C" void kernel_launch(void* const* d_in, const int* in_sizes, int n_in,
                              void* d_out, int out_size, void* d_ws, size_t ws_size,
                              hipStream_t stream) {
    const float* x   = (const float*)d_in[0];
    const int*   adj = (const int*)d_in[1];
    const float* W   = (const float*)d_in[2];
    const float* a   = (const float*)d_in[3];
    float* out = (float*)d_out;

    // workspace: hT bf16 [B][64][N] (2 MB) + s1,s2 fp32 [B*N] (64 KB each)
    //            + masks u64 [B*N][32] (4 MB) + row_m fp32 [B*N] (64 KB)
    char* p = (char*)d_ws;
    unsigned short* hT = (unsigned short*)p;  p += (size_t)Bb * 64 * Nn * sizeof(unsigned short);
    float* s1 = (float*)p;                    p += (size_t)NROWS * sizeof(float);
    float* s2 = (float*)p;                    p += (size_t)NROWS * sizeof(float);
    unsigned long long* masks = (unsigned long long*)p;
    p += (size_t)NROWS * MCH * sizeof(unsigned long long);
    float* row_m = (float*)p;

    gat_prep<<<dim3(Bb * Nn / 32), dim3(256), 0, stream>>>(x, W, a, hT, s1, s2);
    gat_pack<<<dim3(NROWS / 8), dim3(256), 0, stream>>>(adj, s1, s2, masks, row_m);
    gat_attn<<<dim3(NROWS / 16), dim3(512), 0, stream>>>(masks, hT, s1, s2, row_m, out);
}

// Round 6
// 261.907 us; speedup vs baseline: 1.0361x; 1.0361x over previous
//
#include <hip/hip_runtime.h>
#include <cstdint>

#define LRELU_ALPHA 0.2f
#define NEG_INF -9000000000000000.0f
#define L2E 1.4426950408889634f

typedef __bf16 bf16x8 __attribute__((ext_vector_type(8)));
typedef float floatx4 __attribute__((ext_vector_type(4)));
typedef unsigned int uintx4 __attribute__((ext_vector_type(4)));

constexpr int Bb = 8, Nn = 2048, Ff = 64;
constexpr int TJ = 64;             // j-tile width
constexpr int SEGW = 8;            // waves per block = in-block j-slices
constexpr int SLICE = Nn / SEGW;   // 256 j per wave
constexpr int NT = SLICE / TJ;     // 4 tiles per wave
constexpr int NROWS = Bb * Nn;     // 16384 global rows
constexpr int MCH = Nn / 64;       // 32 mask chunks per row

__device__ __forceinline__ unsigned short f2bf(float f) {
    unsigned u = __builtin_bit_cast(unsigned, f);
    u = u + 0x7FFFu + ((u >> 16) & 1u);   // round-to-nearest-even
    return (unsigned short)(u >> 16);
}

__device__ __forceinline__ unsigned cvt_pk_bf16(float lo, float hi) {
    unsigned r;
    asm("v_cvt_pk_bf16_f32 %0, %1, %2" : "=v"(r) : "v"(lo), "v"(hi));
    return r;
}

// order-preserving f32 <-> u32 (for atomicMax over floats incl. negatives)
__device__ __forceinline__ unsigned enc_f32(float f) {
    unsigned u = __builtin_bit_cast(unsigned, f);
    return (u & 0x80000000u) ? ~u : (u | 0x80000000u);
}
__device__ __forceinline__ float dec_f32(unsigned k) {
    unsigned u = (k & 0x80000000u) ? (k & 0x7FFFFFFFu) : ~k;
    return __builtin_bit_cast(float, u);
}

// ---------------- Kernel 1: h = x@W, s1 = h.a1, s2 = h.a2, hT (bf16 T), batch max(s2) -----
// grid 512, block 256 = 4 waves; wave w owns rows il = w*8 + r.
// Also atomicMax-accumulates enc(max s2) per batch -> s2max_enc[b] (upper bound for softmax).
__global__ __launch_bounds__(256) void gat_prep(
    const float* __restrict__ x, const float* __restrict__ W, const float* __restrict__ a,
    unsigned short* __restrict__ hT, float* __restrict__ s1g, float* __restrict__ s2g,
    unsigned* __restrict__ s2max_enc)
{
    constexpr int STR2 = 36;                    // [f][il] stride (bank-stride 18 -> 2-way = free)
    __shared__ unsigned short hblk[64 * STR2];
    const int tid = threadIdx.x;
    const int blk = blockIdx.x;                 // 512 blocks: 64 row-blocks x 8 batches
    const int b  = blk >> 6;
    const int i0 = (blk & 63) * 32;
    const int w    = tid >> 6;
    const int lane = tid & 63;                  // lane = output feature f

    float wcol[64];
    #pragma unroll
    for (int k = 0; k < 64; ++k) wcol[k] = W[k * 64 + lane];
    const float a1 = a[lane], a2 = a[64 + lane];

    float s2w = NEG_INF;                        // wave-max of s2 over its 8 rows
    for (int r = 0; r < 8; ++r) {
        const int il = w * 8 + r;
        const int i  = i0 + il;
        const float* xrow = x + ((size_t)(b * Nn + i)) * 64;   // wave-uniform -> s_loads
        float h0 = 0.f, h1 = 0.f, h2 = 0.f, h3 = 0.f;
        #pragma unroll
        for (int k = 0; k < 64; k += 4) {
            h0 = fmaf(xrow[k],     wcol[k],     h0);
            h1 = fmaf(xrow[k + 1], wcol[k + 1], h1);
            h2 = fmaf(xrow[k + 2], wcol[k + 2], h2);
            h3 = fmaf(xrow[k + 3], wcol[k + 3], h3);
        }
        const float h = (h0 + h1) + (h2 + h3);
        float p1 = h * a1, p2 = h * a2;
        #pragma unroll
        for (int off = 32; off; off >>= 1) {
            p1 += __shfl_xor(p1, off);
            p2 += __shfl_xor(p2, off);
        }
        if (lane == 0) { s1g[b * Nn + i] = p1; s2g[b * Nn + i] = p2; }
        s2w = fmaxf(s2w, p2);                      // p2 identical across lanes post-reduce
        hblk[lane * STR2 + il] = f2bf(h);          // transpose via LDS
    }
    if (lane == 0) atomicMax(&s2max_enc[b], enc_f32(s2w));   // 4 atomics/block, 8 slots
    __syncthreads();
    {
        const int f = tid >> 2, c = (tid & 3) * 8;
        uint4 v = *reinterpret_cast<const uint4*>(&hblk[f * STR2 + c]);
        *reinterpret_cast<uint4*>(hT + ((size_t)b * 64 + f) * Nn + i0 + c) = v;
    }
}

// ---------------- Kernel 2: fused adj-pack + softmax-free attention ------------------------
// Block = 512 threads = 8 waves; block owns 16 rows.
// Phase A: each wave ballot-packs 2 rows of adj (coalesced 134 MB stream, the ONLY adj read)
//          into mk_lds[16][33] (bit l of chunk c = adj[row][c*64+l] > 0).
// Phase B: wave s sweeps j-slice [s*256,(s+1)*256): p = mask ? exp2(ev - m_ub) : 0 directly
//          (m_ub = leaky(s1+batch max s2) >= true row max; normalization cancels the bias).
//          No online softmax, no per-tile shuffles; tiles fully independent.
// ONE barrier between phases + ONE before merge; sum-only merge; normalize + ELU -> out.
__global__ __launch_bounds__(512, 4) void gat_attn(
    const int* __restrict__ adj, const unsigned short* __restrict__ hT,
    const float* __restrict__ s1g, const float* __restrict__ s2g,
    const unsigned* __restrict__ s2max_enc, float* __restrict__ out)
{
    __shared__ unsigned long long mk_lds[16][33];   // +1 pad: bank = 2*row + 2c, conflict-free
    __shared__ float O_lds[SEGW][16][65];
    __shared__ float l_lds[SEGW][16];

    const int tid  = threadIdx.x;
    const int blk  = blockIdx.x;          // 1024 blocks: 128 per batch
    const int b    = blk >> 7;
    const int i0   = (blk & 127) * 16;
    const int s    = tid >> 6;            // wave id = j-slice
    const int lane = tid & 63;
    const int fl   = lane & 15;           // A-row (i) in e-phase; B-col (f) in mfma phase
    const int q    = lane >> 4;           // quad id: k-group selector

    // ---- Phase A: pack this block's 16 adj rows into LDS bitmasks (coalesced) ----
    #pragma unroll
    for (int rr = 0; rr < 2; ++rr) {
        const int rloc = s * 2 + rr;
        const int* ar = adj + ((size_t)(b * Nn + i0 + rloc)) * Nn;
        unsigned long long acc = 0;            // lane c (<32) accumulates chunk c's mask
        #pragma unroll
        for (int cb = 0; cb < MCH; ++cb) {
            const int v = ar[cb * 64 + lane];
            const unsigned long long mb = __ballot(v > 0);   // bit l <-> j = cb*64+l
            if (lane == cb) acc = mb;
        }
        if (lane < 32) mk_lds[rloc][lane] = acc;
    }

    const int i = i0 + fl;                // this lane's score row
    const float s1v = s1g[b * Nn + i];
    const float s2mx = dec_f32(s2max_enc[b]);
    float mub = s1v + s2mx;
    mub = fmaxf(mub, LRELU_ALPHA * mub);  // leaky(s1 + max s2) >= true row max (monotonic)
    const float ci = -mub * L2E;          // exp2 arg bias
    const unsigned short* hTb = hT + (size_t)b * 64 * Nn + s * SLICE;
    const float* s2b = s2g + b * Nn + s * SLICE;

    __syncthreads();

    // ---- Phase B: softmax-free attention over this wave's j-slice ----
    float l = 0.f;
    floatx4 C[4] = {};                    // 4 f-tiles of 16x16 C

    #pragma unroll
    for (int jt = 0; jt < NT; ++jt) {
        const int jloc = jt * TJ;

        const unsigned long long mk = mk_lds[fl][s * NT + jt];
        const float4 sA = *reinterpret_cast<const float4*>(&s2b[jloc + q * 8]);
        const float4 sB = *reinterpret_cast<const float4*>(&s2b[jloc + q * 8 + 4]);
        const float4 sC = *reinterpret_cast<const float4*>(&s2b[jloc + 32 + q * 8]);
        const float4 sD = *reinterpret_cast<const float4*>(&s2b[jloc + 32 + q * 8 + 4]);

        bf16x8 Bv[8];
        #pragma unroll
        for (int u = 0; u < 4; ++u) {
            Bv[2 * u] = *reinterpret_cast<const bf16x8*>(
                hTb + (size_t)(u * 16 + fl) * Nn + jloc + q * 8);
            Bv[2 * u + 1] = *reinterpret_cast<const bf16x8*>(
                hTb + (size_t)(u * 16 + fl) * Nn + jloc + 32 + q * 8);
        }

        const unsigned blo = ((unsigned)(mk >> (q * 8))) & 0xFFu;
        const unsigned bhi = ((unsigned)(mk >> (32 + q * 8))) & 0xFFu;

        // p[k]: j = jloc + tt*32 + q*8 + jj ; p = mask ? exp(e - m_ub) : 0 ; p <= 1
        float p[16];
        {
            const float s2v0[8] = { sA.x, sA.y, sA.z, sA.w, sB.x, sB.y, sB.z, sB.w };
            const float s2v1[8] = { sC.x, sC.y, sC.z, sC.w, sD.x, sD.y, sD.z, sD.w };
            #pragma unroll
            for (int jj = 0; jj < 8; ++jj) {
                float ev = s1v + s2v0[jj];
                ev = fmaxf(ev, LRELU_ALPHA * ev);              // leaky_relu, alpha<1
                const float t = exp2f(fmaf(ev, L2E, ci));
                p[jj] = (blo & (1u << jj)) ? t : 0.f;
                l += p[jj];
            }
            #pragma unroll
            for (int jj = 0; jj < 8; ++jj) {
                float ev = s1v + s2v1[jj];
                ev = fmaxf(ev, LRELU_ALPHA * ev);
                const float t = exp2f(fmaf(ev, L2E, ci));
                p[8 + jj] = (bhi & (1u << jj)) ? t : 0.f;
                l += p[8 + jj];
            }
        }

        // pack p -> bf16 A-fragments
        uintx4 pa, pb;
        #pragma unroll
        for (int d = 0; d < 4; ++d) {
            pa[d] = cvt_pk_bf16(p[2 * d],     p[2 * d + 1]);
            pb[d] = cvt_pk_bf16(p[8 + 2 * d], p[8 + 2 * d + 1]);
        }
        const bf16x8 A0 = __builtin_bit_cast(bf16x8, pa);
        const bf16x8 A1 = __builtin_bit_cast(bf16x8, pb);

        // PV: 4 f-tiles x 2 k-steps
        __builtin_amdgcn_s_setprio(1);
        #pragma unroll
        for (int u = 0; u < 4; ++u) {
            C[u] = __builtin_amdgcn_mfma_f32_16x16x32_bf16(A0, Bv[2 * u],     C[u], 0, 0, 0);
            C[u] = __builtin_amdgcn_mfma_f32_16x16x32_bf16(A1, Bv[2 * u + 1], C[u], 0, 0, 0);
        }
        __builtin_amdgcn_s_setprio(0);
    }

    // one l-reduce per wave (cross-quad), not per tile
    l += __shfl_xor(l, 16);
    l += __shfl_xor(l, 32);

    // ---- in-block merge of the 8 j-slice partials (sum-only: all share m_ub) ----
    #pragma unroll
    for (int u = 0; u < 4; ++u)
        #pragma unroll
        for (int r = 0; r < 4; ++r)
            O_lds[s][q * 4 + r][u * 16 + fl] = C[u][r];
    if (q == 0) l_lds[s][fl] = l;
    __syncthreads();

    // 1024 outputs, 512 threads -> 2 consecutive f each; coalesced float2 store
    const int row = tid >> 5;
    const int f0  = (tid & 31) * 2;

    float lsum = 0.f, acc0 = 0.f, acc1 = 0.f;
    #pragma unroll
    for (int k = 0; k < SEGW; ++k) {
        lsum += l_lds[k][row];
        const float2 ov = *reinterpret_cast<const float2*>(&O_lds[k][row][f0]);
        acc0 += ov.x;
        acc1 += ov.y;
    }
    const float inv = 1.f / lsum;
    float v0 = acc0 * inv, v1 = acc1 * inv;
    v0 = (v0 > 0.f) ? v0 : (exp2f(v0 * L2E) - 1.f);    // elu, alpha=1
    v1 = (v1 > 0.f) ? v1 : (exp2f(v1 * L2E) - 1.f);
    float2 o2; o2.x = v0; o2.y = v1;
    *reinterpret_cast<float2*>(&out[((size_t)(b * Nn + i0 + row)) * 64 + f0]) = o2;
}

extern "C" void kernel_launch(void* const* d_in, const int* in_sizes, int n_in,
                              void* d_out, int out_size, void* d_ws, size_t ws_size,
                              hipStream_t stream) {
    const float* x   = (const float*)d_in[0];
    const int*   adj = (const int*)d_in[1];
    const float* W   = (const float*)d_in[2];
    const float* a   = (const float*)d_in[3];
    float* out = (float*)d_out;

    // workspace: hT bf16 [B][64][N] (2 MB) + s1,s2 fp32 [B*N] (64 KB each)
    //            + s2max_enc u32 [B] (32 B)
    char* p = (char*)d_ws;
    unsigned short* hT = (unsigned short*)p;  p += (size_t)Bb * 64 * Nn * sizeof(unsigned short);
    float* s1 = (float*)p;                    p += (size_t)NROWS * sizeof(float);
    float* s2 = (float*)p;                    p += (size_t)NROWS * sizeof(float);
    unsigned* s2max_enc = (unsigned*)p;

    // init the 8 encoded-max slots to 0 (= minimum in the order-preserving encoding)
    hipMemsetAsync(s2max_enc, 0, Bb * sizeof(unsigned), stream);
    gat_prep<<<dim3(Bb * Nn / 32), dim3(256), 0, stream>>>(x, W, a, hT, s1, s2, s2max_enc);
    gat_attn<<<dim3(NROWS / 16), dim3(512), 0, stream>>>(adj, hT, s1, s2, s2max_enc, out);
}

// Round 7
// 237.272 us; speedup vs baseline: 1.1437x; 1.1038x over previous
//
#include <hip/hip_runtime.h>
#include <cstdint>

#define LRELU_ALPHA 0.2f
#define NEG_INF -9000000000000000.0f
#define L2E 1.4426950408889634f

typedef __bf16 bf16x8 __attribute__((ext_vector_type(8)));
typedef float floatx4 __attribute__((ext_vector_type(4)));
typedef unsigned int uintx4 __attribute__((ext_vector_type(4)));

constexpr int Bb = 8, Nn = 2048, Ff = 64;
constexpr int TJ = 64;             // j-tile width
constexpr int SEGW = 8;            // waves per block = in-block j-slices
constexpr int SLICE = Nn / SEGW;   // 256 j per wave
constexpr int NT = SLICE / TJ;     // 4 tiles per wave
constexpr int NROWS = Bb * Nn;     // 16384 global rows
constexpr int MCH = Nn / 64;       // 32 mask chunks per row

__device__ __forceinline__ unsigned short f2bf(float f) {
    unsigned u = __builtin_bit_cast(unsigned, f);
    u = u + 0x7FFFu + ((u >> 16) & 1u);   // round-to-nearest-even
    return (unsigned short)(u >> 16);
}

__device__ __forceinline__ unsigned cvt_pk_bf16(float lo, float hi) {
    unsigned r;
    asm("v_cvt_pk_bf16_f32 %0, %1, %2" : "=v"(r) : "v"(lo), "v"(hi));
    return r;
}

// ---------------- Kernel 1: h = x@W (fp32), s1 = h.a1, s2 = h.a2, hT (bf16, transposed) ----
// grid 512, block 256 = 4 waves; wave w owns rows il = w*8 + r.
__global__ __launch_bounds__(256) void gat_prep(
    const float* __restrict__ x, const float* __restrict__ W, const float* __restrict__ a,
    unsigned short* __restrict__ hT, float* __restrict__ s1g, float* __restrict__ s2g)
{
    constexpr int STR2 = 36;                    // [f][il] stride (bank-stride 18 -> 2-way = free)
    __shared__ unsigned short hblk[64 * STR2];
    const int tid = threadIdx.x;
    const int blk = blockIdx.x;                 // 512 blocks: 64 row-blocks x 8 batches
    const int b  = blk >> 6;
    const int i0 = (blk & 63) * 32;
    const int w    = tid >> 6;
    const int lane = tid & 63;                  // lane = output feature f

    float wcol[64];
    #pragma unroll
    for (int k = 0; k < 64; ++k) wcol[k] = W[k * 64 + lane];
    const float a1 = a[lane], a2 = a[64 + lane];

    for (int r = 0; r < 8; ++r) {
        const int il = w * 8 + r;
        const int i  = i0 + il;
        const float* xrow = x + ((size_t)(b * Nn + i)) * 64;   // wave-uniform -> s_loads
        float h0 = 0.f, h1 = 0.f, h2 = 0.f, h3 = 0.f;
        #pragma unroll
        for (int k = 0; k < 64; k += 4) {
            h0 = fmaf(xrow[k],     wcol[k],     h0);
            h1 = fmaf(xrow[k + 1], wcol[k + 1], h1);
            h2 = fmaf(xrow[k + 2], wcol[k + 2], h2);
            h3 = fmaf(xrow[k + 3], wcol[k + 3], h3);
        }
        const float h = (h0 + h1) + (h2 + h3);
        float p1 = h * a1, p2 = h * a2;
        #pragma unroll
        for (int off = 32; off; off >>= 1) {
            p1 += __shfl_xor(p1, off);
            p2 += __shfl_xor(p2, off);
        }
        if (lane == 0) { s1g[b * Nn + i] = p1; s2g[b * Nn + i] = p2; }
        hblk[lane * STR2 + il] = f2bf(h);          // transpose via LDS
    }
    __syncthreads();
    {
        const int f = tid >> 2, c = (tid & 3) * 8;
        uint4 v = *reinterpret_cast<const uint4*>(&hblk[f * STR2 + c]);
        *reinterpret_cast<uint4*>(hT + ((size_t)b * 64 + f) * Nn + i0 + c) = v;
    }
}

// ---------------- Kernel 2: fused adj-pack + softmax-free attention ------------------------
// Block = 512 threads = 8 waves; block owns 16 rows. Minimal-dispatch structure (2 kernels).
// Phase A0: in-block batch max of s2 (8 KB, L2-hot) -> m_ub bias; no atomics, no memset.
// Phase A:  each wave ballot-packs 2 rows of adj (the ONLY adj read, fully coalesced
//           134 MB stream) into mk_lds[16][33].
// Phase B:  wave s sweeps j-slice: p = mask ? exp2(ev - m_ub) : 0 (normalization cancels
//           the bias; p <= 1 since m_ub >= true row max). Tiles fully independent.
// ONE barrier between phases + ONE before merge; sum-only merge; normalize + ELU -> out.
__global__ __launch_bounds__(512, 4) void gat_attn(
    const int* __restrict__ adj, const unsigned short* __restrict__ hT,
    const float* __restrict__ s1g, const float* __restrict__ s2g,
    float* __restrict__ out)
{
    __shared__ unsigned long long mk_lds[16][33];   // +1 pad: conflict-free
    __shared__ float smax_lds[SEGW];
    __shared__ float O_lds[SEGW][16][65];
    __shared__ float l_lds[SEGW][16];

    const int tid  = threadIdx.x;
    const int blk  = blockIdx.x;          // 1024 blocks: 128 per batch
    const int b    = blk >> 7;
    const int i0   = (blk & 127) * 16;
    const int s    = tid >> 6;            // wave id = j-slice
    const int lane = tid & 63;
    const int fl   = lane & 15;           // A-row (i) in e-phase; B-col (f) in mfma phase
    const int q    = lane >> 4;           // quad id: k-group selector

    // ---- Phase A0: batch max of s2 (wave s covers s2[b][s*256 .. s*256+255]) ----
    {
        const float4 v = *reinterpret_cast<const float4*>(&s2g[b * Nn + s * SLICE + lane * 4]);
        float sm = fmaxf(fmaxf(v.x, v.y), fmaxf(v.z, v.w));
        #pragma unroll
        for (int off = 32; off; off >>= 1) sm = fmaxf(sm, __shfl_xor(sm, off));
        if (lane == 0) smax_lds[s] = sm;
    }

    // ---- Phase A: pack this block's 16 adj rows into LDS bitmasks (coalesced) ----
    #pragma unroll
    for (int rr = 0; rr < 2; ++rr) {
        const int rloc = s * 2 + rr;
        const int* ar = adj + ((size_t)(b * Nn + i0 + rloc)) * Nn;
        unsigned long long acc = 0;            // lane c (<32) accumulates chunk c's mask
        #pragma unroll
        for (int cb = 0; cb < MCH; ++cb) {
            const int v = ar[cb * 64 + lane];
            const unsigned long long mb = __ballot(v > 0);   // bit l <-> j = cb*64+l
            if (lane == cb) acc = mb;
        }
        if (lane < 32) mk_lds[rloc][lane] = acc;
    }

    const int i = i0 + fl;                // this lane's score row
    const float s1v = s1g[b * Nn + i];
    const unsigned short* hTb = hT + (size_t)b * 64 * Nn + s * SLICE;
    const float* s2b = s2g + b * Nn + s * SLICE;

    __syncthreads();

    float s2mx = smax_lds[0];
    #pragma unroll
    for (int k = 1; k < SEGW; ++k) s2mx = fmaxf(s2mx, smax_lds[k]);
    float mub = s1v + s2mx;
    mub = fmaxf(mub, LRELU_ALPHA * mub);  // leaky(s1 + max s2) >= true row max (monotonic)
    const float ci = -mub * L2E;          // exp2 arg bias

    // ---- Phase B: softmax-free attention over this wave's j-slice ----
    float l = 0.f;
    floatx4 C[4] = {};                    // 4 f-tiles of 16x16 C

    #pragma unroll
    for (int jt = 0; jt < NT; ++jt) {
        const int jloc = jt * TJ;

        const unsigned long long mk = mk_lds[fl][s * NT + jt];
        const float4 sA = *reinterpret_cast<const float4*>(&s2b[jloc + q * 8]);
        const float4 sB = *reinterpret_cast<const float4*>(&s2b[jloc + q * 8 + 4]);
        const float4 sC = *reinterpret_cast<const float4*>(&s2b[jloc + 32 + q * 8]);
        const float4 sD = *reinterpret_cast<const float4*>(&s2b[jloc + 32 + q * 8 + 4]);

        bf16x8 Bv[8];
        #pragma unroll
        for (int u = 0; u < 4; ++u) {
            Bv[2 * u] = *reinterpret_cast<const bf16x8*>(
                hTb + (size_t)(u * 16 + fl) * Nn + jloc + q * 8);
            Bv[2 * u + 1] = *reinterpret_cast<const bf16x8*>(
                hTb + (size_t)(u * 16 + fl) * Nn + jloc + 32 + q * 8);
        }

        const unsigned blo = ((unsigned)(mk >> (q * 8))) & 0xFFu;
        const unsigned bhi = ((unsigned)(mk >> (32 + q * 8))) & 0xFFu;

        // p[k]: j = jloc + tt*32 + q*8 + jj ; p = mask ? exp(e - m_ub) : 0 ; p <= 1
        float p[16];
        {
            const float s2v0[8] = { sA.x, sA.y, sA.z, sA.w, sB.x, sB.y, sB.z, sB.w };
            const float s2v1[8] = { sC.x, sC.y, sC.z, sC.w, sD.x, sD.y, sD.z, sD.w };
            #pragma unroll
            for (int jj = 0; jj < 8; ++jj) {
                float ev = s1v + s2v0[jj];
                ev = fmaxf(ev, LRELU_ALPHA * ev);              // leaky_relu, alpha<1
                const float t = exp2f(fmaf(ev, L2E, ci));
                p[jj] = (blo & (1u << jj)) ? t : 0.f;
                l += p[jj];
            }
            #pragma unroll
            for (int jj = 0; jj < 8; ++jj) {
                float ev = s1v + s2v1[jj];
                ev = fmaxf(ev, LRELU_ALPHA * ev);
                const float t = exp2f(fmaf(ev, L2E, ci));
                p[8 + jj] = (bhi & (1u << jj)) ? t : 0.f;
                l += p[8 + jj];
            }
        }

        // pack p -> bf16 A-fragments
        uintx4 pa, pb;
        #pragma unroll
        for (int d = 0; d < 4; ++d) {
            pa[d] = cvt_pk_bf16(p[2 * d],     p[2 * d + 1]);
            pb[d] = cvt_pk_bf16(p[8 + 2 * d], p[8 + 2 * d + 1]);
        }
        const bf16x8 A0 = __builtin_bit_cast(bf16x8, pa);
        const bf16x8 A1 = __builtin_bit_cast(bf16x8, pb);

        // PV: 4 f-tiles x 2 k-steps
        __builtin_amdgcn_s_setprio(1);
        #pragma unroll
        for (int u = 0; u < 4; ++u) {
            C[u] = __builtin_amdgcn_mfma_f32_16x16x32_bf16(A0, Bv[2 * u],     C[u], 0, 0, 0);
            C[u] = __builtin_amdgcn_mfma_f32_16x16x32_bf16(A1, Bv[2 * u + 1], C[u], 0, 0, 0);
        }
        __builtin_amdgcn_s_setprio(0);
    }

    // one l-reduce per wave (cross-quad), not per tile
    l += __shfl_xor(l, 16);
    l += __shfl_xor(l, 32);

    // ---- in-block merge of the 8 j-slice partials (sum-only: all share m_ub) ----
    #pragma unroll
    for (int u = 0; u < 4; ++u)
        #pragma unroll
        for (int r = 0; r < 4; ++r)
            O_lds[s][q * 4 + r][u * 16 + fl] = C[u][r];
    if (q == 0) l_lds[s][fl] = l;
    __syncthreads();

    // 1024 outputs, 512 threads -> 2 consecutive f each; coalesced float2 store
    const int row = tid >> 5;
    const int f0  = (tid & 31) * 2;

    float lsum = 0.f, acc0 = 0.f, acc1 = 0.f;
    #pragma unroll
    for (int k = 0; k < SEGW; ++k) {
        lsum += l_lds[k][row];
        const float2 ov = *reinterpret_cast<const float2*>(&O_lds[k][row][f0]);
        acc0 += ov.x;
        acc1 += ov.y;
    }
    const float inv = 1.f / lsum;
    float v0 = acc0 * inv, v1 = acc1 * inv;
    v0 = (v0 > 0.f) ? v0 : (exp2f(v0 * L2E) - 1.f);    // elu, alpha=1
    v1 = (v1 > 0.f) ? v1 : (exp2f(v1 * L2E) - 1.f);
    float2 o2; o2.x = v0; o2.y = v1;
    *reinterpret_cast<float2*>(&out[((size_t)(b * Nn + i0 + row)) * 64 + f0]) = o2;
}

extern "C" void kernel_launch(void* const* d_in, const int* in_sizes, int n_in,
                              void* d_out, int out_size, void* d_ws, size_t ws_size,
                              hipStream_t stream) {
    const float* x   = (const float*)d_in[0];
    const int*   adj = (const int*)d_in[1];
    const float* W   = (const float*)d_in[2];
    const float* a   = (const float*)d_in[3];
    float* out = (float*)d_out;

    // workspace: hT bf16 [B][64][N] (2 MB) + s1,s2 fp32 [B*N] (64 KB each)
    char* p = (char*)d_ws;
    unsigned short* hT = (unsigned short*)p;  p += (size_t)Bb * 64 * Nn * sizeof(unsigned short);
    float* s1 = (float*)p;                    p += (size_t)NROWS * sizeof(float);
    float* s2 = (float*)p;

    gat_prep<<<dim3(Bb * Nn / 32), dim3(256), 0, stream>>>(x, W, a, hT, s1, s2);
    gat_attn<<<dim3(NROWS / 16), dim3(512), 0, stream>>>(adj, hT, s1, s2, out);
}

// Round 8
// 230.404 us; speedup vs baseline: 1.1777x; 1.0298x over previous
//
#include <hip/hip_runtime.h>
#include <cstdint>

#define LRELU_ALPHA 0.2f
#define NEG_INF -9000000000000000.0f
#define L2E 1.4426950408889634f

typedef __bf16 bf16x8 __attribute__((ext_vector_type(8)));
typedef float floatx4 __attribute__((ext_vector_type(4)));
typedef unsigned int uintx4 __attribute__((ext_vector_type(4)));

constexpr int Bb = 8, Nn = 2048, Ff = 64;
constexpr int TJ = 64;             // j-tile width
constexpr int SEGW = 8;            // waves per block = in-block j-slices
constexpr int SLICE = Nn / SEGW;   // 256 j per wave
constexpr int NT = SLICE / TJ;     // 4 tiles per wave
constexpr int NROWS = Bb * Nn;     // 16384 global rows

__device__ __forceinline__ unsigned short f2bf(float f) {
    unsigned u = __builtin_bit_cast(unsigned, f);
    u = u + 0x7FFFu + ((u >> 16) & 1u);   // round-to-nearest-even
    return (unsigned short)(u >> 16);
}

__device__ __forceinline__ unsigned cvt_pk_bf16(float lo, float hi) {
    unsigned r;
    asm("v_cvt_pk_bf16_f32 %0, %1, %2" : "=v"(r) : "v"(lo), "v"(hi));
    return r;
}

// ---------------- Kernel 1: h = x@W (fp32), s1 = h.a1, s2 = h.a2, hT (bf16, transposed) ----
// grid 512, block 256 = 4 waves; wave w owns rows il = w*8 + r.
__global__ __launch_bounds__(256) void gat_prep(
    const float* __restrict__ x, const float* __restrict__ W, const float* __restrict__ a,
    unsigned short* __restrict__ hT, float* __restrict__ s1g, float* __restrict__ s2g)
{
    constexpr int STR2 = 36;                    // [f][il] stride (bank-stride 18 -> 2-way = free)
    __shared__ unsigned short hblk[64 * STR2];
    const int tid = threadIdx.x;
    const int blk = blockIdx.x;                 // 512 blocks: 64 row-blocks x 8 batches
    const int b  = blk >> 6;
    const int i0 = (blk & 63) * 32;
    const int w    = tid >> 6;
    const int lane = tid & 63;                  // lane = output feature f

    float wcol[64];
    #pragma unroll
    for (int k = 0; k < 64; ++k) wcol[k] = W[k * 64 + lane];
    const float a1 = a[lane], a2 = a[64 + lane];

    for (int r = 0; r < 8; ++r) {
        const int il = w * 8 + r;
        const int i  = i0 + il;
        const float* xrow = x + ((size_t)(b * Nn + i)) * 64;   // wave-uniform -> s_loads
        float h0 = 0.f, h1 = 0.f, h2 = 0.f, h3 = 0.f;
        #pragma unroll
        for (int k = 0; k < 64; k += 4) {
            h0 = fmaf(xrow[k],     wcol[k],     h0);
            h1 = fmaf(xrow[k + 1], wcol[k + 1], h1);
            h2 = fmaf(xrow[k + 2], wcol[k + 2], h2);
            h3 = fmaf(xrow[k + 3], wcol[k + 3], h3);
        }
        const float h = (h0 + h1) + (h2 + h3);
        float p1 = h * a1, p2 = h * a2;
        #pragma unroll
        for (int off = 32; off; off >>= 1) {
            p1 += __shfl_xor(p1, off);
            p2 += __shfl_xor(p2, off);
        }
        if (lane == 0) { s1g[b * Nn + i] = p1; s2g[b * Nn + i] = p2; }
        hblk[lane * STR2 + il] = f2bf(h);          // transpose via LDS
    }
    __syncthreads();
    {
        const int f = tid >> 2, c = (tid & 3) * 8;
        uint4 v = *reinterpret_cast<const uint4*>(&hblk[f * STR2 + c]);
        *reinterpret_cast<uint4*>(hT + ((size_t)b * 64 + f) * Nn + i0 + c) = v;
    }
}

// ---------------- Kernel 2: fused adj-pack + softmax-free attention (ILP-first) ------------
// Block = 512 threads = 8 waves; block owns 16 rows; wave s sweeps j-slice [s*256,(s+1)*256).
// LDS intentionally >53.3 KB -> 2 blocks/CU -> compiler targets 4 waves/SIMD -> 128-VGPR
// budget (round-7's 38 KB LDS self-capped VGPRs at 56, serializing every load: 80% stall).
// Phase A: 16 batched int4 adj loads per wave (its OWN 16-row x 256-j window), issued BEFORE
//   the barrier (latency overlaps barrier drain); 4 ballots per int4 -> permuted bit layout:
//   word k of group li=s: bit l <-> j = 256*s + 4*l + k. Masks land in 4 u64 REGS per lane.
// Phase B: p = maskbit ? exp2(ev - m_ub) : 0 (m_ub = leaky(s1 + batch max s2) >= row max;
//   normalization cancels the bias). s2 from LDS; tiles fully independent; 8 MFMA/tile.
__global__ __launch_bounds__(512, 4) void gat_attn(
    const int* __restrict__ adj, const unsigned short* __restrict__ hT,
    const float* __restrict__ s1g, const float* __restrict__ s2g,
    float* __restrict__ out)
{
    __shared__ unsigned long long mk_lds[SEGW][16][6];  // [wave][row][4 words + 2 pad]
    __shared__ float s2_lds[Nn];                        // whole batch s2 row (8 KB)
    __shared__ float smax_lds[SEGW];
    __shared__ float O_lds[SEGW][16][65];
    __shared__ float l_lds[SEGW][16];
    __shared__ float lds_pad[2048];                     // occupancy shaping -> 2 blocks/CU

    const int tid  = threadIdx.x;
    const int blk  = blockIdx.x;          // 1024 blocks: 128 per batch
    const int b    = blk >> 7;
    const int i0   = (blk & 127) * 16;
    const int s    = tid >> 6;            // wave id = j-slice
    const int lane = tid & 63;
    const int fl   = lane & 15;           // A-row (i) in e-phase; B-col (f) in mfma phase
    const int q    = lane >> 4;           // quad id: k-group selector

    // ---- A0: stage s2 slice to LDS + wave max -> smax ----
    {
        const float4 v = *reinterpret_cast<const float4*>(&s2g[b * Nn + s * SLICE + lane * 4]);
        *reinterpret_cast<float4*>(&s2_lds[s * SLICE + lane * 4]) = v;
        float sm = fmaxf(fmaxf(v.x, v.y), fmaxf(v.z, v.w));
        #pragma unroll
        for (int off = 32; off; off >>= 1) sm = fmaxf(sm, __shfl_xor(sm, off));
        if (lane == 0) smax_lds[s] = sm;
    }

    const int i = i0 + fl;                // this lane's score row
    const float s1v = s1g[b * Nn + i];
    if (blk == 0x7FFFFFFF) lds_pad[tid] = s1v;   // keep pad alive (never true)

    // ---- Phase A loads: 16 batched int4 reads of THIS wave's adj window, pre-barrier ----
    const int4* adjb = reinterpret_cast<const int4*>(adj + (size_t)(b * Nn + i0) * Nn);
    int4 va[16];
    #pragma unroll
    for (int r = 0; r < 16; ++r)
        va[r] = adjb[(size_t)r * (Nn / 4) + s * 64 + lane];   // row i0+r, j = s*256 + 4*lane + c

    __syncthreads();                       // barrier #1 (smax); adj loads drain here = overlap

    float s2mx = smax_lds[0];
    #pragma unroll
    for (int k = 1; k < SEGW; ++k) s2mx = fmaxf(s2mx, smax_lds[k]);
    float mub = s1v + s2mx;
    mub = fmaxf(mub, LRELU_ALPHA * mub);   // leaky(s1 + max s2) >= true row max (monotonic)
    const float ci = -mub * L2E;           // exp2 arg bias

    // ---- ballots: word k of row r: bit l <-> adj[i0+r][s*256 + 4*l + k] > 0 ----
    {
        unsigned long long acc = 0;
        #pragma unroll
        for (int r = 0; r < 16; ++r) {
            const unsigned long long m0 = __ballot(va[r].x > 0);
            const unsigned long long m1 = __ballot(va[r].y > 0);
            const unsigned long long m2 = __ballot(va[r].z > 0);
            const unsigned long long m3 = __ballot(va[r].w > 0);
            const unsigned long long sel = (lane & 2) ? ((lane & 1) ? m3 : m2)
                                                      : ((lane & 1) ? m1 : m0);
            if ((lane >> 2) == r) acc = sel;       // lane l holds (row l>>2, word l&3)
        }
        mk_lds[s][lane >> 2][lane & 3] = acc;
    }
    asm volatile("s_waitcnt lgkmcnt(0)" ::: "memory");   // wave-local LDS RAW
    // lane's row-fl mask words for the whole slice (all 4 tiles): 4 u64 in regs
    const unsigned long long w0 = mk_lds[s][fl][0];
    const unsigned long long w1 = mk_lds[s][fl][1];
    const unsigned long long w2 = mk_lds[s][fl][2];
    const unsigned long long w3 = mk_lds[s][fl][3];

    const unsigned short* hTb = hT + (size_t)b * 64 * Nn + s * SLICE;
    const float* sl0 = &s2_lds[s * SLICE];

    // ---- Phase B: softmax-free attention over this wave's j-slice ----
    float l = 0.f;
    floatx4 C[4] = {};                    // 4 f-tiles of 16x16 C

    #pragma unroll
    for (int jt = 0; jt < NT; ++jt) {
        const int jloc = jt * TJ;

        bf16x8 Bv[8];
        #pragma unroll
        for (int u = 0; u < 4; ++u) {
            Bv[2 * u] = *reinterpret_cast<const bf16x8*>(
                hTb + (size_t)(u * 16 + fl) * Nn + jloc + q * 8);
            Bv[2 * u + 1] = *reinterpret_cast<const bf16x8*>(
                hTb + (size_t)(u * 16 + fl) * Nn + jloc + 32 + q * 8);
        }

        const float4 sA = *reinterpret_cast<const float4*>(&sl0[jloc + q * 8]);
        const float4 sB = *reinterpret_cast<const float4*>(&sl0[jloc + q * 8 + 4]);
        const float4 sC = *reinterpret_cast<const float4*>(&sl0[jloc + 32 + q * 8]);
        const float4 sD = *reinterpret_cast<const float4*>(&sl0[jloc + 32 + q * 8 + 4]);

        // mask bits: local off = jt*64 + tt*32 + q*8 + jj -> word jj&3, bit jt*16+tt*8+q*2+(jj>>2)
        const unsigned b0 = (unsigned)(jt * 16 + q * 2);
        const unsigned t0w0 = (unsigned)(w0 >> b0),       t0w1 = (unsigned)(w1 >> b0);
        const unsigned t0w2 = (unsigned)(w2 >> b0),       t0w3 = (unsigned)(w3 >> b0);
        const unsigned t1w0 = (unsigned)(w0 >> (b0 + 8)), t1w1 = (unsigned)(w1 >> (b0 + 8));
        const unsigned t1w2 = (unsigned)(w2 >> (b0 + 8)), t1w3 = (unsigned)(w3 >> (b0 + 8));

        float p[16];
        {
            const float s2v0[8] = { sA.x, sA.y, sA.z, sA.w, sB.x, sB.y, sB.z, sB.w };
            const float s2v1[8] = { sC.x, sC.y, sC.z, sC.w, sD.x, sD.y, sD.z, sD.w };
            const unsigned tw0[4] = { t0w0, t0w1, t0w2, t0w3 };
            const unsigned tw1[4] = { t1w0, t1w1, t1w2, t1w3 };
            #pragma unroll
            for (int jj = 0; jj < 8; ++jj) {
                float ev = s1v + s2v0[jj];
                ev = fmaxf(ev, LRELU_ALPHA * ev);              // leaky_relu, alpha<1
                const float t = exp2f(fmaf(ev, L2E, ci));
                p[jj] = ((tw0[jj & 3] >> (jj >> 2)) & 1u) ? t : 0.f;
                l += p[jj];
            }
            #pragma unroll
            for (int jj = 0; jj < 8; ++jj) {
                float ev = s1v + s2v1[jj];
                ev = fmaxf(ev, LRELU_ALPHA * ev);
                const float t = exp2f(fmaf(ev, L2E, ci));
                p[8 + jj] = ((tw1[jj & 3] >> (jj >> 2)) & 1u) ? t : 0.f;
                l += p[8 + jj];
            }
        }

        // pack p -> bf16 A-fragments
        uintx4 pa, pb;
        #pragma unroll
        for (int d = 0; d < 4; ++d) {
            pa[d] = cvt_pk_bf16(p[2 * d],     p[2 * d + 1]);
            pb[d] = cvt_pk_bf16(p[8 + 2 * d], p[8 + 2 * d + 1]);
        }
        const bf16x8 A0 = __builtin_bit_cast(bf16x8, pa);
        const bf16x8 A1 = __builtin_bit_cast(bf16x8, pb);

        // PV: 4 f-tiles x 2 k-steps
        __builtin_amdgcn_s_setprio(1);
        #pragma unroll
        for (int u = 0; u < 4; ++u) {
            C[u] = __builtin_amdgcn_mfma_f32_16x16x32_bf16(A0, Bv[2 * u],     C[u], 0, 0, 0);
            C[u] = __builtin_amdgcn_mfma_f32_16x16x32_bf16(A1, Bv[2 * u + 1], C[u], 0, 0, 0);
        }
        __builtin_amdgcn_s_setprio(0);
    }

    // one l-reduce per wave (cross-quad), not per tile
    l += __shfl_xor(l, 16);
    l += __shfl_xor(l, 32);

    // ---- in-block merge of the 8 j-slice partials (sum-only: all share m_ub) ----
    #pragma unroll
    for (int u = 0; u < 4; ++u)
        #pragma unroll
        for (int r = 0; r < 4; ++r)
            O_lds[s][q * 4 + r][u * 16 + fl] = C[u][r];
    if (q == 0) l_lds[s][fl] = l;
    __syncthreads();                       // barrier #2

    // 1024 outputs, 512 threads -> 2 consecutive f each; coalesced float2 store
    const int row = tid >> 5;
    const int f0  = (tid & 31) * 2;

    float lsum = 0.f, acc0 = 0.f, acc1 = 0.f;
    #pragma unroll
    for (int k = 0; k < SEGW; ++k) {
        lsum += l_lds[k][row];
        const float2 ov = *reinterpret_cast<const float2*>(&O_lds[k][row][f0]);
        acc0 += ov.x;
        acc1 += ov.y;
    }
    const float inv = 1.f / lsum;
    float v0 = acc0 * inv, v1 = acc1 * inv;
    v0 = (v0 > 0.f) ? v0 : (exp2f(v0 * L2E) - 1.f);    // elu, alpha=1
    v1 = (v1 > 0.f) ? v1 : (exp2f(v1 * L2E) - 1.f);
    float2 o2; o2.x = v0; o2.y = v1;
    *reinterpret_cast<float2*>(&out[((size_t)(b * Nn + i0 + row)) * 64 + f0]) = o2;
}

extern "C" void kernel_launch(void* const* d_in, const int* in_sizes, int n_in,
                              void* d_out, int out_size, void* d_ws, size_t ws_size,
                              hipStream_t stream) {
    const float* x   = (const float*)d_in[0];
    const int*   adj = (const int*)d_in[1];
    const float* W   = (const float*)d_in[2];
    const float* a   = (const float*)d_in[3];
    float* out = (float*)d_out;

    // workspace: hT bf16 [B][64][N] (2 MB) + s1,s2 fp32 [B*N] (64 KB each)
    char* p = (char*)d_ws;
    unsigned short* hT = (unsigned short*)p;  p += (size_t)Bb * 64 * Nn * sizeof(unsigned short);
    float* s1 = (float*)p;                    p += (size_t)NROWS * sizeof(float);
    float* s2 = (float*)p;

    gat_prep<<<dim3(Bb * Nn / 32), dim3(256), 0, stream>>>(x, W, a, hT, s1, s2);
    gat_attn<<<dim3(NROWS / 16), dim3(512), 0, stream>>>(adj, hT, s1, s2, out);
}